// Round 1
// baseline (39.600 us; speedup 1.0000x reference)
//
#include <hip/hip_runtime.h>
#include <math.h>

// CTC batch cost, faithful to the jax reference.
// B=64 blocks; phase 1: gather log-probs of needed classes into LDS;
// phase 2: wave-0 register DP over T with shfl_up for alpha[s-1], alpha[s-2].

#define NEGV (-1e30f)
#define EPSV (1e-7f)

constexpr int B = 64, T = 128, C = 4000, L = 48;
constexpr int S = 2 * L + 1;     // 97
constexpr int BLANK = C - 1;     // 3999

__global__ __launch_bounds__(256) void ctc_kernel(
    const int* __restrict__ y_true,     // [B, L]
    const float* __restrict__ y_pred,   // [B, T, C] probabilities
    const int* __restrict__ label_len,  // [B, 1]
    float* __restrict__ out)            // [B, 1]
{
    const int b = blockIdx.x;
    const int tid = threadIdx.x;

    __shared__ float lp_lab[T][L];   // 24 KB: log p of label j at time t
    __shared__ float lp_blank[T];    // 512 B: log p of blank at time t
    __shared__ int   lab_s[L];
    __shared__ int   ll_s;

    // Load labels; pad beyond label_length with blank (as reference does).
    if (tid < L) {
        int ll = label_len[b];
        if (tid == 0) ll_s = ll;
        int v = y_true[b * L + tid];
        lab_s[tid] = (tid < ll) ? v : BLANK;
    }
    __syncthreads();

    // ---- Phase 1: gather T*(L+1) = 6272 log-probs into LDS ----
    const float* yp = y_pred + (size_t)b * T * C;
    for (int g = tid; g < T * (L + 1); g += 256) {
        int t = g / (L + 1);
        int j = g - t * (L + 1);
        int cls = (j < L) ? lab_s[j] : BLANK;
        float v = __logf(yp[t * C + cls] + EPSV);
        if (j < L) lp_lab[t][j] = v;
        else       lp_blank[t] = v;
    }
    __syncthreads();

    if (tid >= 64) return;   // DP runs on wave 0 only
    const int lane = tid;

    const int ll = ll_s;
    // lane l owns states s0 = 2l (blank state) and s1 = 2l+1 (label l).
    const int myLab   = (lane < L) ? lab_s[lane] : BLANK;
    const int prevLab = (lane >= 1 && lane - 1 < L) ? lab_s[lane - 1] : BLANK;
    // skip s-2 -> s allowed only for odd states with distinct non-blank label
    const bool allow2 = (lane >= 1) && (myLab != BLANK) && (myLab != prevLab);

    // alpha at t=0: only s=0 and s=1 reachable.
    float a0 = (lane == 0) ? lp_blank[0]  : NEGV;   // state 2l
    float a1 = (lane == 0) ? lp_lab[0][0] : NEGV;   // state 2l+1

    for (int t = 1; t < T; ++t) {
        float pa1 = __shfl_up(a1, 1);   // alpha[2l-1] from lane l-1

        // state s0 = 2l: terms {alpha[2l], alpha[2l-1], NEG (no skip into blank)}
        float c00 = a0;
        float c01 = (lane > 0) ? pa1 : NEGV;
        float c02 = NEGV;
        float lpb = lp_blank[t];
        float m0 = fmaxf(fmaxf(c00, c01), c02);
        float n0 = m0 + __logf(__expf(c00 - m0) + __expf(c01 - m0) + __expf(c02 - m0)) + lpb;

        // state s1 = 2l+1: terms {alpha[2l+1], alpha[2l], allow2 ? alpha[2l-1] : NEG}
        float c10 = a1;
        float c11 = a0;
        float c12 = allow2 ? pa1 : NEGV;
        float lpl = (lane < L) ? lp_lab[t][lane] : 0.0f;
        float m1 = fmaxf(fmaxf(c10, c11), c12);
        float n1 = m1 + __logf(__expf(c10 - m1) + __expf(c11 - m1) + __expf(c12 - m1)) + lpl;

        a0 = n0;
        a1 = (lane < L) ? n1 : NEGV;   // states beyond S stay dead
    }

    // Valid endings: s = 2*ll (blank, lane ll slot 0) or s = 2*ll-1 (lane ll-1 slot 1).
    float ab = __shfl(a0, ll);
    float al = __shfl(a1, ll - 1);
    if (lane == 0) {
        float m = fmaxf(ab, al);
        float loss = -(m + __logf(__expf(ab - m) + __expf(al - m)));
        out[b] = loss;
    }
}

extern "C" void kernel_launch(void* const* d_in, const int* in_sizes, int n_in,
                              void* d_out, int out_size, void* d_ws, size_t ws_size,
                              hipStream_t stream) {
    const int*   y_true       = (const int*)d_in[0];
    const float* y_pred       = (const float*)d_in[1];
    const int*   label_length = (const int*)d_in[2];
    float*       out          = (float*)d_out;

    ctc_kernel<<<B, 256, 0, stream>>>(y_true, y_pred, label_length, out);
}

// Round 3
// 31.892 us; speedup vs baseline: 1.2417x; 1.2417x over previous
//
#include <hip/hip_runtime.h>
#include <math.h>

// CTC batch cost. Two-kernel pipeline:
//  K1 (1568 blocks): gather log2(y_pred[b,t,cls]+eps) for the 49 needed
//     classes per (b,t) into workspace  -> full-chip latency hiding.
//  K2 (64 blocks): stage [T][49] slice into LDS (coalesced float4), then
//     wave-0 register DP over T using DPP wave_shr:1 for alpha[s-1].
// Falls back to a fused single kernel if ws_size is too small.

#define NEGV (-1e30f)
#define EPSV (1e-7f)

constexpr int B = 64, T = 128, C = 4000, L = 48;
constexpr int BLANK = C - 1;       // 3999
constexpr int NCLS = L + 1;        // 49: slots 0..47 = labels, 48 = blank
constexpr int TOTAL = B * T * NCLS;

// lane shift up by 1 across the full wave via DPP wave_shr:1 (VALU latency,
// much faster than ds_bpermute). Lane 0 receives `old` (= NEGV boundary).
__device__ __forceinline__ float dpp_shr1_neg(float x) {
    int r = __builtin_amdgcn_update_dpp(__float_as_int(NEGV), __float_as_int(x),
                                        0x138 /*wave_shr:1*/, 0xF, 0xF, false);
    return __int_as_float(r);
}

// ---------------- Kernel 1: gather ----------------
__global__ __launch_bounds__(256) void gather_kernel(
    const int* __restrict__ y_true,     // [B, L]
    const float* __restrict__ y_pred,   // [B, T, C]
    const int* __restrict__ label_len,  // [B, 1]
    float* __restrict__ lp_ws)          // [B, T, NCLS] log2-probs
{
    int idx = blockIdx.x * 256 + threadIdx.x;
    if (idx >= TOTAL) return;
    int j  = idx % NCLS;
    int bt = idx / NCLS;
    int b  = bt / T;
    int t  = bt - b * T;
    int cls = BLANK;
    if (j < L) {
        int ll = label_len[b];
        cls = (j < ll) ? y_true[b * L + j] : BLANK;
    }
    float p = y_pred[((size_t)b * T + t) * C + cls];
    lp_ws[idx] = log2f(p + EPSV);
}

// ---------------- Kernel 2: DP ----------------
__global__ __launch_bounds__(256) void dp_kernel(
    const int* __restrict__ y_true,
    const int* __restrict__ label_len,
    const float* __restrict__ lp_ws,    // [B, T, NCLS]
    float* __restrict__ out)            // [B, 1]
{
    const int b = blockIdx.x;
    const int tid = threadIdx.x;

    __shared__ float lp_s[T * NCLS];    // 25088 B
    __shared__ int   lab_s[L];
    __shared__ int   ll_s;

    if (tid < L) {
        int ll = label_len[b];
        if (tid == 0) ll_s = ll;
        int v = y_true[b * L + tid];
        lab_s[tid] = (tid < ll) ? v : BLANK;   // pad with blank as reference
    }

    // coalesced float4 stage: 6272 floats = 1568 float4
    const float4* src = (const float4*)(lp_ws + (size_t)b * T * NCLS);
    float4* dst = (float4*)lp_s;
    for (int i = tid; i < (T * NCLS) / 4; i += 256) dst[i] = src[i];
    __syncthreads();

    if (tid >= 64) return;              // DP on wave 0 only
    const int lane = tid;
    const int ll = ll_s;

    // lane l owns states s0 = 2l (blank) and s1 = 2l+1 (label l)
    const int myLab   = (lane < L) ? lab_s[lane] : BLANK;
    const int prevLab = (lane >= 1 && lane - 1 < L) ? lab_s[lane - 1] : BLANK;
    const bool allow2 = (lane >= 1) && (myLab != BLANK) && (myLab != prevLab);

    float a0 = (lane == 0) ? lp_s[48] : NEGV;   // t=0, state 0 (blank)
    float a1 = (lane == 0) ? lp_s[0]  : NEGV;   // t=0, state 1 (label 0)

    // prefetch lp for t=1
    float lpb_n = lp_s[1 * NCLS + 48];
    float lpl_n = (lane < L) ? lp_s[1 * NCLS + lane] : 0.0f;

    for (int t = 1; t < T; ++t) {
        float lpb = lpb_n, lpl = lpl_n;
        int tn = (t + 1 < T) ? t + 1 : t;
        lpb_n = lp_s[tn * NCLS + 48];
        lpl_n = (lane < L) ? lp_s[tn * NCLS + lane] : 0.0f;

        float pa1 = dpp_shr1_neg(a1);   // alpha[2l-1] from lane l-1 (lane0 -> NEG)

        // state 2l: lse2(a0, pa1) + lpb   (skip into blank never allowed)
        float m0 = fmaxf(a0, pa1);
        float n0 = fminf(a0, pa1);
        float r0 = m0 + log2f(1.0f + exp2f(n0 - m0)) + lpb;

        // state 2l+1: lse3(a1, a0, allow2 ? pa1 : NEG) + lpl
        float c12 = allow2 ? pa1 : NEGV;
        float m1 = fmaxf(fmaxf(a1, a0), c12);
        float r1 = m1 + log2f(exp2f(a1 - m1) + exp2f(a0 - m1) +
                              exp2f(c12 - m1)) + lpl;

        a0 = r0;
        a1 = (lane < L) ? r1 : NEGV;    // states beyond S stay dead
    }

    float ab = __shfl(a0, ll);          // alpha[2*ll]
    float al = __shfl(a1, ll - 1);      // alpha[2*ll-1]
    if (lane == 0) {
        float m = fmaxf(ab, al);
        float ll2 = m + log2f(exp2f(ab - m) + exp2f(al - m));
        out[b] = -ll2 * 0.69314718055994531f;   // back to natural log
    }
}

// ---------------- Fallback: fused single kernel (small ws) ----------------
__global__ __launch_bounds__(256) void ctc_fused_kernel(
    const int* __restrict__ y_true,
    const float* __restrict__ y_pred,
    const int* __restrict__ label_len,
    float* __restrict__ out)
{
    const int b = blockIdx.x;
    const int tid = threadIdx.x;

    __shared__ float lp_s[T * NCLS];
    __shared__ int   lab_s[L];
    __shared__ int   ll_s;

    if (tid < L) {
        int ll = label_len[b];
        if (tid == 0) ll_s = ll;
        int v = y_true[b * L + tid];
        lab_s[tid] = (tid < ll) ? v : BLANK;
    }
    __syncthreads();

    const float* yp = y_pred + (size_t)b * T * C;
    for (int g = tid; g < T * NCLS; g += 256) {
        int t = g / NCLS;
        int j = g - t * NCLS;
        int cls = (j < L) ? lab_s[j] : BLANK;
        lp_s[g] = log2f(yp[t * C + cls] + EPSV);
    }
    __syncthreads();

    if (tid >= 64) return;
    const int lane = tid;
    const int ll = ll_s;
    const int myLab   = (lane < L) ? lab_s[lane] : BLANK;
    const int prevLab = (lane >= 1 && lane - 1 < L) ? lab_s[lane - 1] : BLANK;
    const bool allow2 = (lane >= 1) && (myLab != BLANK) && (myLab != prevLab);

    float a0 = (lane == 0) ? lp_s[48] : NEGV;
    float a1 = (lane == 0) ? lp_s[0]  : NEGV;

    float lpb_n = lp_s[1 * NCLS + 48];
    float lpl_n = (lane < L) ? lp_s[1 * NCLS + lane] : 0.0f;

    for (int t = 1; t < T; ++t) {
        float lpb = lpb_n, lpl = lpl_n;
        int tn = (t + 1 < T) ? t + 1 : t;
        lpb_n = lp_s[tn * NCLS + 48];
        lpl_n = (lane < L) ? lp_s[tn * NCLS + lane] : 0.0f;

        float pa1 = dpp_shr1_neg(a1);

        float m0 = fmaxf(a0, pa1);
        float n0 = fminf(a0, pa1);
        float r0 = m0 + log2f(1.0f + exp2f(n0 - m0)) + lpb;

        float c12 = allow2 ? pa1 : NEGV;
        float m1 = fmaxf(fmaxf(a1, a0), c12);
        float r1 = m1 + log2f(exp2f(a1 - m1) + exp2f(a0 - m1) +
                              exp2f(c12 - m1)) + lpl;

        a0 = r0;
        a1 = (lane < L) ? r1 : NEGV;
    }

    float ab = __shfl(a0, ll);
    float al = __shfl(a1, ll - 1);
    if (lane == 0) {
        float m = fmaxf(ab, al);
        float ll2 = m + log2f(exp2f(ab - m) + exp2f(al - m));
        out[b] = -ll2 * 0.69314718055994531f;
    }
}

extern "C" void kernel_launch(void* const* d_in, const int* in_sizes, int n_in,
                              void* d_out, int out_size, void* d_ws, size_t ws_size,
                              hipStream_t stream) {
    const int*   y_true       = (const int*)d_in[0];
    const float* y_pred       = (const float*)d_in[1];
    const int*   label_length = (const int*)d_in[2];
    float*       out          = (float*)d_out;

    const size_t need = (size_t)TOTAL * sizeof(float);
    if (ws_size >= need) {
        float* lp_ws = (float*)d_ws;
        gather_kernel<<<(TOTAL + 255) / 256, 256, 0, stream>>>(
            y_true, y_pred, label_length, lp_ws);
        dp_kernel<<<B, 256, 0, stream>>>(y_true, label_length, lp_ws, out);
    } else {
        ctc_fused_kernel<<<B, 256, 0, stream>>>(y_true, y_pred, label_length, out);
    }
}